// Round 1
// baseline (3768.764 us; speedup 1.0000x reference)
//
#include <hip/hip_runtime.h>

#define HID 128
#define NNODES 4096
#define T 4
#define N_PER 512

// ---------------------------------------------------------------------------
// Encoders: build x[4096][128]
// row 0 = ground_param; rows 1..2048 = blocks (per-type MLP);
// rows 2049..3072 = obstacles; rows 3073..4095 = targets
// ---------------------------------------------------------------------------
__global__ __launch_bounds__(128) void encode_kernel(
    const float* __restrict__ blocks, const float* __restrict__ obstacles,
    const float* __restrict__ targets,
    const float* __restrict__ Wb1, const float* __restrict__ bb1,
    const float* __restrict__ Wb2, const float* __restrict__ bb2,
    const float* __restrict__ Wo1, const float* __restrict__ bo1,
    const float* __restrict__ Wo2, const float* __restrict__ bo2,
    const float* __restrict__ Wt1, const float* __restrict__ bt1,
    const float* __restrict__ Wt2, const float* __restrict__ bt2,
    const float* __restrict__ ground, float* __restrict__ x) {
  int n = blockIdx.x;
  int j = threadIdx.x;
  __shared__ float in_s[32];
  __shared__ float h_s[128];
  if (n == 0) {
    x[j] = ground[j];
    return;
  }
  const float *W1, *b1, *W2, *b2, *inp;
  int D;
  if (n <= 2048) {
    int b = n - 1;
    int t = b >> 9;  // type
    inp = blocks + (size_t)b * 33;
    D = 32;
    W1 = Wb1 + (size_t)t * 32 * HID;
    b1 = bb1 + (size_t)t * HID;
    W2 = Wb2 + (size_t)t * HID * HID;
    b2 = bb2 + (size_t)t * HID;
  } else if (n <= 3072) {
    int o = n - 2049;
    inp = obstacles + (size_t)o * 16;
    D = 16;
    W1 = Wo1; b1 = bo1; W2 = Wo2; b2 = bo2;
  } else {
    int tg = n - 3073;
    inp = targets + (size_t)tg * 16;
    D = 16;
    W1 = Wt1; b1 = bt1; W2 = Wt2; b2 = bt2;
  }
  if (j < D) in_s[j] = inp[j];
  __syncthreads();
  float acc = b1[j];
  for (int d = 0; d < D; d++) acc += in_s[d] * W1[d * HID + j];
  h_s[j] = fmaxf(acc, 0.f);
  __syncthreads();
  float acc2 = b2[j];
  for (int k = 0; k < HID; k++) acc2 += h_s[k] * W2[k * HID + j];
  x[(size_t)n * HID + j] = acc2;
}

// ---------------------------------------------------------------------------
// QKV projections: for each of 12 (mat,head) pairs, out = x @ W[h]
// grid (12, 128): 32 rows per block, 256 threads
// ---------------------------------------------------------------------------
__global__ __launch_bounds__(256) void qkv_kernel(
    const float* __restrict__ x, const float* __restrict__ Wk,
    const float* __restrict__ Wq, const float* __restrict__ Wv,
    float* __restrict__ kd, float* __restrict__ qd, float* __restrict__ vd) {
  int m = blockIdx.x;           // 0..11
  int h = m & 3;
  int sel = m >> 2;             // 0=k, 1=q, 2=v
  const float* W = (sel == 0 ? Wk : (sel == 1 ? Wq : Wv)) + (size_t)h * HID * HID;
  float* out = (sel == 0 ? kd : (sel == 1 ? qd : vd)) + (size_t)h * NNODES * HID;
  int r0 = blockIdx.y * 32;
  __shared__ float xs[32][132];
  int t = threadIdx.x;
  for (int i = t; i < 32 * 32; i += 256) {
    int r = i >> 5, c = (i & 31) * 4;
    *(float4*)&xs[r][c] = *(const float4*)(x + (size_t)(r0 + r) * HID + c);
  }
  __syncthreads();
  int j = t & 127;
  int rh = t >> 7;  // 0/1
  float acc[16];
#pragma unroll
  for (int i = 0; i < 16; i++) acc[i] = 0.f;
  for (int d = 0; d < HID; d += 4) {
    float w0 = W[(d + 0) * HID + j];
    float w1 = W[(d + 1) * HID + j];
    float w2 = W[(d + 2) * HID + j];
    float w3 = W[(d + 3) * HID + j];
#pragma unroll
    for (int i = 0; i < 16; i++) {
      float4 xv = *(const float4*)&xs[rh * 16 + i][d];
      acc[i] = fmaf(xv.x, w0, fmaf(xv.y, w1, fmaf(xv.z, w2, fmaf(xv.w, w3, acc[i]))));
    }
  }
#pragma unroll
  for (int i = 0; i < 16; i++)
    out[(size_t)(r0 + rh * 16 + i) * HID + j] = acc[i];
}

// ---------------------------------------------------------------------------
// Flash attention per head: out_h[h][n][:] = softmax(q[n]·k[m]) @ v
// grid (4, 128): head h, 32 query rows per block, 256 threads.
// Thread (qi = t>>3, g = t&7): computes scores for kj = 4g..4g+3,
// owns out columns g*16..g*16+15.
// ---------------------------------------------------------------------------
__global__ __launch_bounds__(256) void attn_kernel(
    const float* __restrict__ qg, const float* __restrict__ kg,
    const float* __restrict__ vg, float* __restrict__ outh) {
  int h = blockIdx.x;
  int q0 = blockIdx.y * 32;
  const float* qh = qg + (size_t)h * NNODES * HID;
  const float* kh = kg + (size_t)h * NNODES * HID;
  const float* vh = vg + (size_t)h * NNODES * HID;
  __shared__ float qs[32][132];
  __shared__ float ks[32][132];
  __shared__ float vs[32][132];
  __shared__ float ps[32][36];
  int t = threadIdx.x;
  for (int i = t; i < 32 * 32; i += 256) {
    int r = i >> 5, c = (i & 31) * 4;
    *(float4*)&qs[r][c] = *(const float4*)(qh + (size_t)(q0 + r) * HID + c);
  }
  int qi = t >> 3;  // 0..31
  int g = t & 7;    // 0..7
  float out[16];
#pragma unroll
  for (int i = 0; i < 16; i++) out[i] = 0.f;
  float run_m = -1e30f, run_l = 0.f;
  __syncthreads();
  for (int kt = 0; kt < NNODES / 32; kt++) {
    for (int i = t; i < 32 * 32; i += 256) {
      int r = i >> 5, c = (i & 31) * 4;
      *(float4*)&ks[r][c] = *(const float4*)(kh + (size_t)(kt * 32 + r) * HID + c);
      *(float4*)&vs[r][c] = *(const float4*)(vh + (size_t)(kt * 32 + r) * HID + c);
    }
    __syncthreads();
    float s0 = 0.f, s1 = 0.f, s2 = 0.f, s3 = 0.f;
#pragma unroll 4
    for (int d = 0; d < HID; d += 4) {
      float4 q4 = *(const float4*)&qs[qi][d];
      float4 k0 = *(const float4*)&ks[4 * g + 0][d];
      float4 k1 = *(const float4*)&ks[4 * g + 1][d];
      float4 k2 = *(const float4*)&ks[4 * g + 2][d];
      float4 k3 = *(const float4*)&ks[4 * g + 3][d];
      s0 = fmaf(q4.x, k0.x, fmaf(q4.y, k0.y, fmaf(q4.z, k0.z, fmaf(q4.w, k0.w, s0))));
      s1 = fmaf(q4.x, k1.x, fmaf(q4.y, k1.y, fmaf(q4.z, k1.z, fmaf(q4.w, k1.w, s1))));
      s2 = fmaf(q4.x, k2.x, fmaf(q4.y, k2.y, fmaf(q4.z, k2.z, fmaf(q4.w, k2.w, s2))));
      s3 = fmaf(q4.x, k3.x, fmaf(q4.y, k3.y, fmaf(q4.z, k3.z, fmaf(q4.w, k3.w, s3))));
    }
    // online softmax over this tile
    float mt = fmaxf(fmaxf(s0, s1), fmaxf(s2, s3));
#pragma unroll
    for (int o = 1; o < 8; o <<= 1) mt = fmaxf(mt, __shfl_xor(mt, o));
    float nm = fmaxf(run_m, mt);
    float p0 = __expf(s0 - nm), p1 = __expf(s1 - nm);
    float p2 = __expf(s2 - nm), p3 = __expf(s3 - nm);
    float lt = p0 + p1 + p2 + p3;
#pragma unroll
    for (int o = 1; o < 8; o <<= 1) lt += __shfl_xor(lt, o);
    float scale = __expf(run_m - nm);
    run_l = run_l * scale + lt;
    run_m = nm;
#pragma unroll
    for (int i = 0; i < 16; i++) out[i] *= scale;
    *(float4*)&ps[qi][4 * g] = make_float4(p0, p1, p2, p3);
    __syncthreads();
    // PV: accumulate out[qi][g*16..] += p[qi][kj] * v[kj][...]
#pragma unroll 4
    for (int kj = 0; kj < 32; kj++) {
      float p = ps[qi][kj];
      float4 v0 = *(const float4*)&vs[kj][g * 16 + 0];
      float4 v1 = *(const float4*)&vs[kj][g * 16 + 4];
      float4 v2 = *(const float4*)&vs[kj][g * 16 + 8];
      float4 v3 = *(const float4*)&vs[kj][g * 16 + 12];
      out[0] = fmaf(p, v0.x, out[0]);   out[1] = fmaf(p, v0.y, out[1]);
      out[2] = fmaf(p, v0.z, out[2]);   out[3] = fmaf(p, v0.w, out[3]);
      out[4] = fmaf(p, v1.x, out[4]);   out[5] = fmaf(p, v1.y, out[5]);
      out[6] = fmaf(p, v1.z, out[6]);   out[7] = fmaf(p, v1.w, out[7]);
      out[8] = fmaf(p, v2.x, out[8]);   out[9] = fmaf(p, v2.y, out[9]);
      out[10] = fmaf(p, v2.z, out[10]); out[11] = fmaf(p, v2.w, out[11]);
      out[12] = fmaf(p, v3.x, out[12]); out[13] = fmaf(p, v3.y, out[13]);
      out[14] = fmaf(p, v3.z, out[14]); out[15] = fmaf(p, v3.w, out[15]);
    }
    __syncthreads();
  }
  float inv = 1.f / run_l;
  float* orow = outh + ((size_t)h * NNODES + q0 + qi) * HID + g * 16;
#pragma unroll
  for (int i = 0; i < 16; i += 4) {
    float4 o4 = make_float4(out[i] * inv, out[i + 1] * inv, out[i + 2] * inv, out[i + 3] * inv);
    *(float4*)&orow[i] = o4;
  }
}

// ---------------------------------------------------------------------------
// Gating: x = x + relu((x + sum_h Wm[h]*out_h) @ Wg + bg)
// grid 128: 32 rows/block, 256 threads
// ---------------------------------------------------------------------------
__global__ __launch_bounds__(256) void gate_kernel(
    float* __restrict__ x, const float* __restrict__ outh,
    const float* __restrict__ Wm, const float* __restrict__ Wg,
    const float* __restrict__ bg) {
  int r0 = blockIdx.x * 32;
  __shared__ float ss[32][132];
  int t = threadIdx.x;
  float wm0 = Wm[0], wm1 = Wm[1], wm2 = Wm[2], wm3 = Wm[3];
  for (int i = t; i < 32 * 32; i += 256) {
    int r = i >> 5, c = (i & 31) * 4;
    size_t off = (size_t)(r0 + r) * HID + c;
    float4 xv = *(const float4*)(x + off);
    float4 o0 = *(const float4*)(outh + 0ul * NNODES * HID + off);
    float4 o1 = *(const float4*)(outh + 1ul * NNODES * HID + off);
    float4 o2 = *(const float4*)(outh + 2ul * NNODES * HID + off);
    float4 o3 = *(const float4*)(outh + 3ul * NNODES * HID + off);
    float4 s;
    s.x = xv.x + wm0 * o0.x + wm1 * o1.x + wm2 * o2.x + wm3 * o3.x;
    s.y = xv.y + wm0 * o0.y + wm1 * o1.y + wm2 * o2.y + wm3 * o3.y;
    s.z = xv.z + wm0 * o0.z + wm1 * o1.z + wm2 * o2.z + wm3 * o3.z;
    s.w = xv.w + wm0 * o0.w + wm1 * o1.w + wm2 * o2.w + wm3 * o3.w;
    *(float4*)&ss[r][c] = s;
  }
  __syncthreads();
  int j = t & 127;
  int rh = t >> 7;
  float acc[16];
#pragma unroll
  for (int i = 0; i < 16; i++) acc[i] = bg[j];
  for (int d = 0; d < HID; d += 4) {
    float w0 = Wg[(d + 0) * HID + j];
    float w1 = Wg[(d + 1) * HID + j];
    float w2 = Wg[(d + 2) * HID + j];
    float w3 = Wg[(d + 3) * HID + j];
#pragma unroll
    for (int i = 0; i < 16; i++) {
      float4 sv = *(const float4*)&ss[rh * 16 + i][d];
      acc[i] = fmaf(sv.x, w0, fmaf(sv.y, w1, fmaf(sv.z, w2, fmaf(sv.w, w3, acc[i]))));
    }
  }
#pragma unroll
  for (int i = 0; i < 16; i++) {
    size_t r = (size_t)(r0 + rh * 16 + i) * HID + j;
    x[r] = x[r] + fmaxf(acc[i], 0.f);
  }
}

// ---------------------------------------------------------------------------
// Column sum of x over all 4096 rows (for mean)
// ---------------------------------------------------------------------------
__global__ __launch_bounds__(128) void colsum_kernel(const float* __restrict__ x,
                                                     float* __restrict__ xsum) {
  int j = threadIdx.x;
  int r0 = blockIdx.x * 32;
  float s = 0.f;
  for (int r = 0; r < 32; r++) s += x[(size_t)(r0 + r) * HID + j];
  atomicAdd(&xsum[j], s);
}

// ---------------------------------------------------------------------------
// G = mean(x) @ Wglob + bglob ; q_ground = concat(x[0], G) @ Wgr + bgr
// ---------------------------------------------------------------------------
__global__ __launch_bounds__(128) void ground_kernel(
    const float* __restrict__ x, const float* __restrict__ xsum,
    const float* __restrict__ Wglob, const float* __restrict__ bglob,
    const float* __restrict__ Wgr, const float* __restrict__ bgr,
    float* __restrict__ G, float* __restrict__ dout) {
  __shared__ float xm[128];
  __shared__ float Gs[128];
  int j = threadIdx.x;
  xm[j] = xsum[j] * (1.f / 4096.f);
  __syncthreads();
  float acc = bglob[j];
  for (int d = 0; d < 128; d++) acc += xm[d] * Wglob[d * 128 + j];
  G[j] = acc;
  Gs[j] = acc;
  __syncthreads();
  if (j < 8) {
    float a = bgr[j];
    for (int d = 0; d < 128; d++) a += x[d] * Wgr[d * 8 + j];
    for (int d = 0; d < 128; d++) a += Gs[d] * Wgr[(128 + d) * 8 + j];
    dout[j] = a;
  }
}

// ---------------------------------------------------------------------------
// q_blocks: feat = [x[1+i], G] @ Wd[type] + bd[type]
// grid 64: 32 block-rows per block, 256 threads; thread = (r = t>>3, a = t&7)
// ---------------------------------------------------------------------------
__global__ __launch_bounds__(256) void qblocks_kernel(
    const float* __restrict__ x, const float* __restrict__ G,
    const float* __restrict__ Wd, const float* __restrict__ bd,
    float* __restrict__ dout) {
  int r0 = blockIdx.x * 32;
  int tt = r0 >> 9;  // type (32 | 512 so one type per block)
  __shared__ float xs[32][132];
  __shared__ float Gs[128];
  int t = threadIdx.x;
  if (t < 128) Gs[t] = G[t];
  for (int i = t; i < 32 * 32; i += 256) {
    int r = i >> 5, c = (i & 31) * 4;
    *(float4*)&xs[r][c] = *(const float4*)(x + (size_t)(1 + r0 + r) * HID + c);
  }
  __syncthreads();
  int r = t >> 3, a = t & 7;
  const float* Wt = Wd + (size_t)tt * 256 * 8;
  float acc = bd[tt * 8 + a];
  for (int d = 0; d < 128; d++) acc += xs[r][d] * Wt[d * 8 + a];
  for (int d = 0; d < 128; d++) acc += Gs[d] * Wt[(128 + d) * 8 + a];
  dout[8 + (size_t)(r0 + r) * 8 + a] = acc;
}

// ---------------------------------------------------------------------------
extern "C" void kernel_launch(void* const* d_in, const int* in_sizes, int n_in,
                              void* d_out, int out_size, void* d_ws, size_t ws_size,
                              hipStream_t stream) {
  const float* blocks    = (const float*)d_in[0];
  const float* obstacles = (const float*)d_in[1];
  const float* targets   = (const float*)d_in[2];
  const float* Wb1 = (const float*)d_in[3];
  const float* bb1 = (const float*)d_in[4];
  const float* Wb2 = (const float*)d_in[5];
  const float* bb2 = (const float*)d_in[6];
  const float* Wd  = (const float*)d_in[7];
  const float* bd  = (const float*)d_in[8];
  const float* Wo1 = (const float*)d_in[9];
  const float* bo1 = (const float*)d_in[10];
  const float* Wo2 = (const float*)d_in[11];
  const float* bo2 = (const float*)d_in[12];
  const float* Wt1 = (const float*)d_in[13];
  const float* bt1 = (const float*)d_in[14];
  const float* Wt2 = (const float*)d_in[15];
  const float* bt2 = (const float*)d_in[16];
  const float* ground = (const float*)d_in[17];
  const float* Wk = (const float*)d_in[18];
  const float* Wq = (const float*)d_in[19];
  const float* Wv = (const float*)d_in[20];
  const float* Wm = (const float*)d_in[21];
  const float* Wg = (const float*)d_in[22];
  const float* bg = (const float*)d_in[23];
  const float* Wglob = (const float*)d_in[24];
  const float* bglob = (const float*)d_in[25];
  const float* Wgr = (const float*)d_in[26];
  const float* bgr = (const float*)d_in[27];

  float* ws = (float*)d_ws;
  float* x    = ws;                               // 4096*128
  float* q    = x + (size_t)NNODES * HID;         // 4*4096*128
  float* k    = q + 4ul * NNODES * HID;
  float* v    = k + 4ul * NNODES * HID;
  float* outh = v + 4ul * NNODES * HID;
  float* xsum = outh + 4ul * NNODES * HID;        // 128
  float* G    = xsum + 128;                       // 128
  float* dout = (float*)d_out;

  encode_kernel<<<NNODES, 128, 0, stream>>>(
      blocks, obstacles, targets, Wb1, bb1, Wb2, bb2, Wo1, bo1, Wo2, bo2,
      Wt1, bt1, Wt2, bt2, ground, x);

  for (int round = 0; round < 3; round++) {
    qkv_kernel<<<dim3(12, NNODES / 32), 256, 0, stream>>>(x, Wk, Wq, Wv, k, q, v);
    attn_kernel<<<dim3(4, NNODES / 32), 256, 0, stream>>>(q, k, v, outh);
    gate_kernel<<<NNODES / 32, 256, 0, stream>>>(x, outh, Wm, Wg, bg);
  }

  hipMemsetAsync(xsum, 0, 128 * sizeof(float), stream);
  colsum_kernel<<<NNODES / 32, 128, 0, stream>>>(x, xsum);
  ground_kernel<<<1, 128, 0, stream>>>(x, xsum, Wglob, bglob, Wgr, bgr, G, dout);
  qblocks_kernel<<<64, 256, 0, stream>>>(x, G, Wd, bd, dout);
}

// Round 4
// 1045.927 us; speedup vs baseline: 3.6033x; 3.6033x over previous
//
#include <hip/hip_runtime.h>

#define HID 128
#define NNODES 4096
#define T 4
#define N_PER 512

typedef unsigned short u16;
typedef __attribute__((ext_vector_type(8))) short bf16x8;
typedef __attribute__((ext_vector_type(4))) float f32x4;

#define MFMA(a, b, c) __builtin_amdgcn_mfma_f32_16x16x32_bf16((a), (b), (c), 0, 0, 0)

__device__ __forceinline__ u16 bfhi(float f) {
  union { float f; unsigned u; } v; v.f = f;
  return (u16)(v.u >> 16);
}
__device__ __forceinline__ float bff(u16 h) {
  union { float f; unsigned u; } v; v.u = ((unsigned)h) << 16;
  return v.f;
}

// ---------------------------------------------------------------------------
// Encoders: build x[4096][128] (fp32)
// ---------------------------------------------------------------------------
__global__ __launch_bounds__(128) void encode_kernel(
    const float* __restrict__ blocks, const float* __restrict__ obstacles,
    const float* __restrict__ targets,
    const float* __restrict__ Wb1, const float* __restrict__ bb1,
    const float* __restrict__ Wb2, const float* __restrict__ bb2,
    const float* __restrict__ Wo1, const float* __restrict__ bo1,
    const float* __restrict__ Wo2, const float* __restrict__ bo2,
    const float* __restrict__ Wt1, const float* __restrict__ bt1,
    const float* __restrict__ Wt2, const float* __restrict__ bt2,
    const float* __restrict__ ground, float* __restrict__ x) {
  int n = blockIdx.x;
  int j = threadIdx.x;
  __shared__ float in_s[32];
  __shared__ float h_s[128];
  if (n == 0) {
    x[j] = ground[j];
    return;
  }
  const float *W1, *b1, *W2, *b2, *inp;
  int D;
  if (n <= 2048) {
    int b = n - 1;
    int t = b >> 9;
    inp = blocks + (size_t)b * 33;
    D = 32;
    W1 = Wb1 + (size_t)t * 32 * HID;
    b1 = bb1 + (size_t)t * HID;
    W2 = Wb2 + (size_t)t * HID * HID;
    b2 = bb2 + (size_t)t * HID;
  } else if (n <= 3072) {
    int o = n - 2049;
    inp = obstacles + (size_t)o * 16;
    D = 16;
    W1 = Wo1; b1 = bo1; W2 = Wo2; b2 = bo2;
  } else {
    int tg = n - 3073;
    inp = targets + (size_t)tg * 16;
    D = 16;
    W1 = Wt1; b1 = bt1; W2 = Wt2; b2 = bt2;
  }
  if (j < D) in_s[j] = inp[j];
  __syncthreads();
  float acc = b1[j];
  for (int d = 0; d < D; d++) acc += in_s[d] * W1[d * HID + j];
  h_s[j] = fmaxf(acc, 0.f);
  __syncthreads();
  float acc2 = b2[j];
  for (int k = 0; k < HID; k++) acc2 += h_s[k] * W2[k * HID + j];
  x[(size_t)n * HID + j] = acc2;
}

// ---------------------------------------------------------------------------
// QKV projections -> split bf16 (hi/lo).  K,Q stored [h][node][d];
// V stored TRANSPOSED [h][d][node] (each thread holds an output column ->
// contiguous 16-node bf16x8 stores, no extra transpose pass).
// grid (12, 128): 32 rows per block, 256 threads
// ---------------------------------------------------------------------------
__global__ __launch_bounds__(256) void qkv_kernel(
    const float* __restrict__ x, const float* __restrict__ Wk,
    const float* __restrict__ Wq, const float* __restrict__ Wv,
    u16* __restrict__ khi, u16* __restrict__ klo,
    u16* __restrict__ qhi, u16* __restrict__ qlo,
    u16* __restrict__ vthi, u16* __restrict__ vtlo) {
  int m = blockIdx.x;
  int h = m & 3;
  int sel = m >> 2;  // 0=k, 1=q, 2=v
  const float* W = (sel == 0 ? Wk : (sel == 1 ? Wq : Wv)) + (size_t)h * HID * HID;
  int r0 = blockIdx.y * 32;
  __shared__ float xs[32][132];
  int t = threadIdx.x;
  for (int i = t; i < 32 * 32; i += 256) {
    int r = i >> 5, c = (i & 31) * 4;
    *(float4*)&xs[r][c] = *(const float4*)(x + (size_t)(r0 + r) * HID + c);
  }
  __syncthreads();
  int j = t & 127;
  int rh = t >> 7;
  float acc[16];
#pragma unroll
  for (int i = 0; i < 16; i++) acc[i] = 0.f;
  for (int d = 0; d < HID; d += 4) {
    float w0 = W[(d + 0) * HID + j];
    float w1 = W[(d + 1) * HID + j];
    float w2 = W[(d + 2) * HID + j];
    float w3 = W[(d + 3) * HID + j];
#pragma unroll
    for (int i = 0; i < 16; i++) {
      float4 xv = *(const float4*)&xs[rh * 16 + i][d];
      acc[i] = fmaf(xv.x, w0, fmaf(xv.y, w1, fmaf(xv.z, w2, fmaf(xv.w, w3, acc[i]))));
    }
  }
  if (sel == 2) {
    __align__(16) u16 hb[16], lb[16];
#pragma unroll
    for (int i = 0; i < 16; i++) {
      float v = acc[i];
      u16 hi = bfhi(v);
      hb[i] = hi;
      lb[i] = bfhi(v - bff(hi));
    }
    u16* dh = vthi + ((size_t)(h * HID + j)) * NNODES + r0 + rh * 16;
    u16* dl = vtlo + ((size_t)(h * HID + j)) * NNODES + r0 + rh * 16;
    *(bf16x8*)dh = *(const bf16x8*)hb;
    *(bf16x8*)(dh + 8) = *(const bf16x8*)(hb + 8);
    *(bf16x8*)dl = *(const bf16x8*)lb;
    *(bf16x8*)(dl + 8) = *(const bf16x8*)(lb + 8);
  } else {
    u16* oh = (sel == 0 ? khi : qhi);
    u16* ol = (sel == 0 ? klo : qlo);
#pragma unroll
    for (int i = 0; i < 16; i++) {
      int row = r0 + rh * 16 + i;
      float v = acc[i];
      u16 hi = bfhi(v);
      oh[((size_t)h * NNODES + row) * HID + j] = hi;
      ol[((size_t)h * NNODES + row) * HID + j] = bfhi(v - bff(hi));
    }
  }
}

// ---------------------------------------------------------------------------
// MFMA flash attention, split-bf16 (3-term) for QK^T and PV.
// grid (4 heads, 64 q-tiles), 256 threads = 4 waves x 16 q-rows, K-tile 32.
// LDS rows padded: K rows 272B, VT/P rows 80B (banks spread, 16B aligned).
// mfma_f32_16x16x32_bf16 layouts: A/B: row|col=lane&15, k=(lane>>4)*8+i;
// C: col=lane&15, row=(lane>>4)*4+reg  [guide m89].
// ---------------------------------------------------------------------------
__global__ __launch_bounds__(256) void attn_kernel(
    const u16* __restrict__ qhi, const u16* __restrict__ qlo,
    const u16* __restrict__ khi, const u16* __restrict__ klo,
    const u16* __restrict__ vthi, const u16* __restrict__ vtlo,
    float* __restrict__ outh) {
  int h = blockIdx.x;
  int q0 = blockIdx.y * 64;
  __shared__ __align__(16) u16 Kls[2][32 * 136];   // [hi/lo][node*136 + d]
  __shared__ __align__(16) u16 Vls[2][128 * 40];   // [hi/lo][d*40 + node]
  __shared__ __align__(16) u16 Pls[4][2][16 * 40]; // [wave][hi/lo][q*40 + node]
  int t = threadIdx.x;
  int w = t >> 6;
  int l = t & 63;
  int lr = l & 15;
  int lg = l >> 4;

  // Q fragments (A operand): row = lr, k = lg*8 + i, 4 chunks of K=32
  int qrow = q0 + w * 16 + lr;
  const u16* qbh = qhi + ((size_t)h * NNODES + qrow) * HID + lg * 8;
  const u16* qbl = qlo + ((size_t)h * NNODES + qrow) * HID + lg * 8;
  bf16x8 qfh[4], qfl[4];
#pragma unroll
  for (int c = 0; c < 4; c++) {
    qfh[c] = *(const bf16x8*)(qbh + c * 32);
    qfl[c] = *(const bf16x8*)(qbl + c * 32);
  }

  f32x4 out[8];
#pragma unroll
  for (int i = 0; i < 8; i++) out[i] = (f32x4){0.f, 0.f, 0.f, 0.f};
  float run_m[4], run_l[4];
#pragma unroll
  for (int r = 0; r < 4; r++) { run_m[r] = -1e30f; run_l[r] = 0.f; }

  const u16* kbh = khi + (size_t)h * NNODES * HID;
  const u16* kbl = klo + (size_t)h * NNODES * HID;
  const u16* vbh = vthi + (size_t)h * HID * NNODES;
  const u16* vbl = vtlo + (size_t)h * HID * NNODES;

  for (int kt = 0; kt < NNODES / 32; kt++) {
    // ---- stage K (row-major, pad 272B) and VT (d-major, pad 80B) ----
#pragma unroll
    for (int i = 0; i < 2; i++) {
      int flat = i * 256 + t;
      int node = flat >> 4, ch = flat & 15;
      *(bf16x8*)&Kls[0][node * 136 + ch * 8] =
          *(const bf16x8*)(kbh + ((size_t)(kt * 32 + node)) * HID + ch * 8);
      *(bf16x8*)&Kls[1][node * 136 + ch * 8] =
          *(const bf16x8*)(kbl + ((size_t)(kt * 32 + node)) * HID + ch * 8);
      int d = flat >> 2, c2 = flat & 3;
      *(bf16x8*)&Vls[0][d * 40 + c2 * 8] =
          *(const bf16x8*)(vbh + (size_t)d * NNODES + kt * 32 + c2 * 8);
      *(bf16x8*)&Vls[1][d * 40 + c2 * 8] =
          *(const bf16x8*)(vbl + (size_t)d * NNODES + kt * 32 + c2 * 8);
    }
    __syncthreads();

    // ---- QK^T: e(16q x 32k) = Q(16x128) K^T, 3-term split ----
    f32x4 ehh[2], ehl[2], elh[2];
#pragma unroll
    for (int ti = 0; ti < 2; ti++) {
      ehh[ti] = (f32x4){0.f, 0.f, 0.f, 0.f};
      ehl[ti] = (f32x4){0.f, 0.f, 0.f, 0.f};
      elh[ti] = (f32x4){0.f, 0.f, 0.f, 0.f};
    }
#pragma unroll
    for (int c = 0; c < 4; c++) {
#pragma unroll
      for (int ti = 0; ti < 2; ti++) {
        bf16x8 bh = *(const bf16x8*)&Kls[0][(ti * 16 + lr) * 136 + c * 32 + lg * 8];
        bf16x8 bl = *(const bf16x8*)&Kls[1][(ti * 16 + lr) * 136 + c * 32 + lg * 8];
        ehh[ti] = MFMA(qfh[c], bh, ehh[ti]);
        ehl[ti] = MFMA(qfh[c], bl, ehl[ti]);
        elh[ti] = MFMA(qfl[c], bh, elh[ti]);
      }
    }
    f32x4 e0 = ehh[0] + ehl[0] + elh[0];
    f32x4 e1 = ehh[1] + ehl[1] + elh[1];

    // ---- online softmax (rows live in lane groups; reduce over lr) ----
    float sc[4];
#pragma unroll
    for (int r = 0; r < 4; r++) {
      float m2 = fmaxf(e0[r], e1[r]);
      m2 = fmaxf(m2, __shfl_xor(m2, 1));
      m2 = fmaxf(m2, __shfl_xor(m2, 2));
      m2 = fmaxf(m2, __shfl_xor(m2, 4));
      m2 = fmaxf(m2, __shfl_xor(m2, 8));
      float nm = fmaxf(run_m[r], m2);
      sc[r] = __expf(run_m[r] - nm);
      run_m[r] = nm;
      float p0 = __expf(e0[r] - nm);
      float p1 = __expf(e1[r] - nm);
      float lt = p0 + p1;
      lt += __shfl_xor(lt, 1);
      lt += __shfl_xor(lt, 2);
      lt += __shfl_xor(lt, 4);
      lt += __shfl_xor(lt, 8);
      run_l[r] = run_l[r] * sc[r] + lt;
      int prow = 4 * lg + r;
      u16 p0h = bfhi(p0);
      u16 p1h = bfhi(p1);
      Pls[w][0][prow * 40 + lr] = p0h;
      Pls[w][0][prow * 40 + 16 + lr] = p1h;
      Pls[w][1][prow * 40 + lr] = bfhi(p0 - bff(p0h));
      Pls[w][1][prow * 40 + 16 + lr] = bfhi(p1 - bff(p1h));
    }
#pragma unroll
    for (int dt = 0; dt < 8; dt++) {
      out[dt][0] *= sc[0];
      out[dt][1] *= sc[1];
      out[dt][2] *= sc[2];
      out[dt][3] *= sc[3];
    }

    // ---- PV: out(16q x 128d) += P(16x32) V(32x128), 3-term split ----
    bf16x8 ah = *(const bf16x8*)&Pls[w][0][lr * 40 + lg * 8];
    bf16x8 al = *(const bf16x8*)&Pls[w][1][lr * 40 + lg * 8];
#pragma unroll
    for (int dt = 0; dt < 8; dt++) {
      bf16x8 bh = *(const bf16x8*)&Vls[0][(dt * 16 + lr) * 40 + lg * 8];
      bf16x8 bl = *(const bf16x8*)&Vls[1][(dt * 16 + lr) * 40 + lg * 8];
      out[dt] = MFMA(ah, bh, out[dt]);
      out[dt] = MFMA(ah, bl, out[dt]);
      out[dt] = MFMA(al, bh, out[dt]);
    }
    __syncthreads();
  }

  float inv[4];
#pragma unroll
  for (int r = 0; r < 4; r++) inv[r] = 1.f / run_l[r];
  float* ob = outh + ((size_t)h * NNODES + q0 + w * 16) * HID;
#pragma unroll
  for (int dt = 0; dt < 8; dt++)
#pragma unroll
    for (int r = 0; r < 4; r++)
      ob[(size_t)(4 * lg + r) * HID + dt * 16 + lr] = out[dt][r] * inv[r];
}

// ---------------------------------------------------------------------------
// Gating: x = x + relu((x + sum_h Wm[h]*out_h) @ Wg + bg)
// ---------------------------------------------------------------------------
__global__ __launch_bounds__(256) void gate_kernel(
    float* __restrict__ x, const float* __restrict__ outh,
    const float* __restrict__ Wm, const float* __restrict__ Wg,
    const float* __restrict__ bg) {
  int r0 = blockIdx.x * 32;
  __shared__ float ss[32][132];
  int t = threadIdx.x;
  float wm0 = Wm[0], wm1 = Wm[1], wm2 = Wm[2], wm3 = Wm[3];
  for (int i = t; i < 32 * 32; i += 256) {
    int r = i >> 5, c = (i & 31) * 4;
    size_t off = (size_t)(r0 + r) * HID + c;
    float4 xv = *(const float4*)(x + off);
    float4 o0 = *(const float4*)(outh + 0ul * NNODES * HID + off);
    float4 o1 = *(const float4*)(outh + 1ul * NNODES * HID + off);
    float4 o2 = *(const float4*)(outh + 2ul * NNODES * HID + off);
    float4 o3 = *(const float4*)(outh + 3ul * NNODES * HID + off);
    float4 s;
    s.x = xv.x + wm0 * o0.x + wm1 * o1.x + wm2 * o2.x + wm3 * o3.x;
    s.y = xv.y + wm0 * o0.y + wm1 * o1.y + wm2 * o2.y + wm3 * o3.y;
    s.z = xv.z + wm0 * o0.z + wm1 * o1.z + wm2 * o2.z + wm3 * o3.z;
    s.w = xv.w + wm0 * o0.w + wm1 * o1.w + wm2 * o2.w + wm3 * o3.w;
    *(float4*)&ss[r][c] = s;
  }
  __syncthreads();
  int j = t & 127;
  int rh = t >> 7;
  float acc[16];
#pragma unroll
  for (int i = 0; i < 16; i++) acc[i] = bg[j];
  for (int d = 0; d < HID; d += 4) {
    float w0 = Wg[(d + 0) * HID + j];
    float w1 = Wg[(d + 1) * HID + j];
    float w2 = Wg[(d + 2) * HID + j];
    float w3 = Wg[(d + 3) * HID + j];
#pragma unroll
    for (int i = 0; i < 16; i++) {
      float4 sv = *(const float4*)&ss[rh * 16 + i][d];
      acc[i] = fmaf(sv.x, w0, fmaf(sv.y, w1, fmaf(sv.z, w2, fmaf(sv.w, w3, acc[i]))));
    }
  }
#pragma unroll
  for (int i = 0; i < 16; i++) {
    size_t r = (size_t)(r0 + rh * 16 + i) * HID + j;
    x[r] = x[r] + fmaxf(acc[i], 0.f);
  }
}

// ---------------------------------------------------------------------------
__global__ __launch_bounds__(128) void colsum_kernel(const float* __restrict__ x,
                                                     float* __restrict__ xsum) {
  int j = threadIdx.x;
  int r0 = blockIdx.x * 32;
  float s = 0.f;
  for (int r = 0; r < 32; r++) s += x[(size_t)(r0 + r) * HID + j];
  atomicAdd(&xsum[j], s);
}

__global__ __launch_bounds__(128) void ground_kernel(
    const float* __restrict__ x, const float* __restrict__ xsum,
    const float* __restrict__ Wglob, const float* __restrict__ bglob,
    const float* __restrict__ Wgr, const float* __restrict__ bgr,
    float* __restrict__ G, float* __restrict__ dout) {
  __shared__ float xm[128];
  __shared__ float Gs[128];
  int j = threadIdx.x;
  xm[j] = xsum[j] * (1.f / 4096.f);
  __syncthreads();
  float acc = bglob[j];
  for (int d = 0; d < 128; d++) acc += xm[d] * Wglob[d * 128 + j];
  G[j] = acc;
  Gs[j] = acc;
  __syncthreads();
  if (j < 8) {
    float a = bgr[j];
    for (int d = 0; d < 128; d++) a += x[d] * Wgr[d * 8 + j];
    for (int d = 0; d < 128; d++) a += Gs[d] * Wgr[(128 + d) * 8 + j];
    dout[j] = a;
  }
}

__global__ __launch_bounds__(256) void qblocks_kernel(
    const float* __restrict__ x, const float* __restrict__ G,
    const float* __restrict__ Wd, const float* __restrict__ bd,
    float* __restrict__ dout) {
  int r0 = blockIdx.x * 32;
  int tt = r0 >> 9;
  __shared__ float xs[32][132];
  __shared__ float Gs[128];
  int t = threadIdx.x;
  if (t < 128) Gs[t] = G[t];
  for (int i = t; i < 32 * 32; i += 256) {
    int r = i >> 5, c = (i & 31) * 4;
    *(float4*)&xs[r][c] = *(const float4*)(x + (size_t)(1 + r0 + r) * HID + c);
  }
  __syncthreads();
  int r = t >> 3, a = t & 7;
  const float* Wt = Wd + (size_t)tt * 256 * 8;
  float acc = bd[tt * 8 + a];
  for (int d = 0; d < 128; d++) acc += xs[r][d] * Wt[d * 8 + a];
  for (int d = 0; d < 128; d++) acc += Gs[d] * Wt[(128 + d) * 8 + a];
  dout[8 + (size_t)(r0 + r) * 8 + a] = acc;
}

// ---------------------------------------------------------------------------
extern "C" void kernel_launch(void* const* d_in, const int* in_sizes, int n_in,
                              void* d_out, int out_size, void* d_ws, size_t ws_size,
                              hipStream_t stream) {
  const float* blocks    = (const float*)d_in[0];
  const float* obstacles = (const float*)d_in[1];
  const float* targets   = (const float*)d_in[2];
  const float* Wb1 = (const float*)d_in[3];
  const float* bb1 = (const float*)d_in[4];
  const float* Wb2 = (const float*)d_in[5];
  const float* bb2 = (const float*)d_in[6];
  const float* Wd  = (const float*)d_in[7];
  const float* bd  = (const float*)d_in[8];
  const float* Wo1 = (const float*)d_in[9];
  const float* bo1 = (const float*)d_in[10];
  const float* Wo2 = (const float*)d_in[11];
  const float* bo2 = (const float*)d_in[12];
  const float* Wt1 = (const float*)d_in[13];
  const float* bt1 = (const float*)d_in[14];
  const float* Wt2 = (const float*)d_in[15];
  const float* bt2 = (const float*)d_in[16];
  const float* ground = (const float*)d_in[17];
  const float* Wk = (const float*)d_in[18];
  const float* Wq = (const float*)d_in[19];
  const float* Wv = (const float*)d_in[20];
  const float* Wm = (const float*)d_in[21];
  const float* Wg = (const float*)d_in[22];
  const float* bg = (const float*)d_in[23];
  const float* Wglob = (const float*)d_in[24];
  const float* bglob = (const float*)d_in[25];
  const float* Wgr = (const float*)d_in[26];
  const float* bgr = (const float*)d_in[27];

  float* ws = (float*)d_ws;
  float* x    = ws;                          // 524288 f32
  float* outh = x + 524288;                  // 2097152 f32
  float* xsum = outh + 2097152;              // 128
  float* G    = xsum + 128;                  // 128
  u16* qhi  = (u16*)(G + 128);               // each 2097152 u16 (4 MB)
  u16* qlo  = qhi + 2097152;
  u16* khi  = qlo + 2097152;
  u16* klo  = khi + 2097152;
  u16* vthi = klo + 2097152;
  u16* vtlo = vthi + 2097152;
  float* dout = (float*)d_out;

  encode_kernel<<<NNODES, 128, 0, stream>>>(
      blocks, obstacles, targets, Wb1, bb1, Wb2, bb2, Wo1, bo1, Wo2, bo2,
      Wt1, bt1, Wt2, bt2, ground, x);

  for (int round = 0; round < 3; round++) {
    qkv_kernel<<<dim3(12, NNODES / 32), 256, 0, stream>>>(
        x, Wk, Wq, Wv, khi, klo, qhi, qlo, vthi, vtlo);
    attn_kernel<<<dim3(4, NNODES / 64), 256, 0, stream>>>(
        qhi, qlo, khi, klo, vthi, vtlo, outh);
    gate_kernel<<<NNODES / 32, 256, 0, stream>>>(x, outh, Wm, Wg, bg);
  }

  hipMemsetAsync(xsum, 0, 128 * sizeof(float), stream);
  colsum_kernel<<<NNODES / 32, 128, 0, stream>>>(x, xsum);
  ground_kernel<<<1, 128, 0, stream>>>(x, xsum, Wglob, bglob, Wgr, bgr, G, dout);
  qblocks_kernel<<<64, 256, 0, stream>>>(x, G, Wd, bd, dout);
}

// Round 5
// 867.802 us; speedup vs baseline: 4.3429x; 1.2053x over previous
//
#include <hip/hip_runtime.h>

#define HID 128
#define NNODES 4096
#define T 4
#define N_PER 512
#define NSPLIT 3

typedef unsigned short u16;
typedef __attribute__((ext_vector_type(8))) short bf16x8;
typedef __attribute__((ext_vector_type(4))) float f32x4;

#define MFMA(a, b, c) __builtin_amdgcn_mfma_f32_16x16x32_bf16((a), (b), (c), 0, 0, 0)

__device__ __forceinline__ u16 bfhi(float f) {
  union { float f; unsigned u; } v; v.f = f;
  return (u16)(v.u >> 16);
}
__device__ __forceinline__ float bff(u16 h) {
  union { float f; unsigned u; } v; v.u = ((unsigned)h) << 16;
  return v.f;
}

// ---------------------------------------------------------------------------
// Encoders: build x[4096][128] (fp32)
// ---------------------------------------------------------------------------
__global__ __launch_bounds__(128) void encode_kernel(
    const float* __restrict__ blocks, const float* __restrict__ obstacles,
    const float* __restrict__ targets,
    const float* __restrict__ Wb1, const float* __restrict__ bb1,
    const float* __restrict__ Wb2, const float* __restrict__ bb2,
    const float* __restrict__ Wo1, const float* __restrict__ bo1,
    const float* __restrict__ Wo2, const float* __restrict__ bo2,
    const float* __restrict__ Wt1, const float* __restrict__ bt1,
    const float* __restrict__ Wt2, const float* __restrict__ bt2,
    const float* __restrict__ ground, float* __restrict__ x) {
  int n = blockIdx.x;
  int j = threadIdx.x;
  __shared__ float in_s[32];
  __shared__ float h_s[128];
  if (n == 0) {
    x[j] = ground[j];
    return;
  }
  const float *W1, *b1, *W2, *b2, *inp;
  int D;
  if (n <= 2048) {
    int b = n - 1;
    int t = b >> 9;
    inp = blocks + (size_t)b * 33;
    D = 32;
    W1 = Wb1 + (size_t)t * 32 * HID;
    b1 = bb1 + (size_t)t * HID;
    W2 = Wb2 + (size_t)t * HID * HID;
    b2 = bb2 + (size_t)t * HID;
  } else if (n <= 3072) {
    int o = n - 2049;
    inp = obstacles + (size_t)o * 16;
    D = 16;
    W1 = Wo1; b1 = bo1; W2 = Wo2; b2 = bo2;
  } else {
    int tg = n - 3073;
    inp = targets + (size_t)tg * 16;
    D = 16;
    W1 = Wt1; b1 = bt1; W2 = Wt2; b2 = bt2;
  }
  if (j < D) in_s[j] = inp[j];
  __syncthreads();
  float acc = b1[j];
  for (int d = 0; d < D; d++) acc += in_s[d] * W1[d * HID + j];
  h_s[j] = fmaxf(acc, 0.f);
  __syncthreads();
  float acc2 = b2[j];
  for (int k = 0; k < HID; k++) acc2 += h_s[k] * W2[k * HID + j];
  x[(size_t)n * HID + j] = acc2;
}

// ---------------------------------------------------------------------------
// QKV projections -> split bf16 (hi/lo).  K,Q stored [h][node][d];
// V stored TRANSPOSED [h][d][node].
// ---------------------------------------------------------------------------
__global__ __launch_bounds__(256) void qkv_kernel(
    const float* __restrict__ x, const float* __restrict__ Wk,
    const float* __restrict__ Wq, const float* __restrict__ Wv,
    u16* __restrict__ khi, u16* __restrict__ klo,
    u16* __restrict__ qhi, u16* __restrict__ qlo,
    u16* __restrict__ vthi, u16* __restrict__ vtlo) {
  int m = blockIdx.x;
  int h = m & 3;
  int sel = m >> 2;  // 0=k, 1=q, 2=v
  const float* W = (sel == 0 ? Wk : (sel == 1 ? Wq : Wv)) + (size_t)h * HID * HID;
  int r0 = blockIdx.y * 32;
  __shared__ float xs[32][132];
  int t = threadIdx.x;
  for (int i = t; i < 32 * 32; i += 256) {
    int r = i >> 5, c = (i & 31) * 4;
    *(float4*)&xs[r][c] = *(const float4*)(x + (size_t)(r0 + r) * HID + c);
  }
  __syncthreads();
  int j = t & 127;
  int rh = t >> 7;
  float acc[16];
#pragma unroll
  for (int i = 0; i < 16; i++) acc[i] = 0.f;
  for (int d = 0; d < HID; d += 4) {
    float w0 = W[(d + 0) * HID + j];
    float w1 = W[(d + 1) * HID + j];
    float w2 = W[(d + 2) * HID + j];
    float w3 = W[(d + 3) * HID + j];
#pragma unroll
    for (int i = 0; i < 16; i++) {
      float4 xv = *(const float4*)&xs[rh * 16 + i][d];
      acc[i] = fmaf(xv.x, w0, fmaf(xv.y, w1, fmaf(xv.z, w2, fmaf(xv.w, w3, acc[i]))));
    }
  }
  if (sel == 2) {
    __align__(16) u16 hb[16], lb[16];
#pragma unroll
    for (int i = 0; i < 16; i++) {
      float v = acc[i];
      u16 hi = bfhi(v);
      hb[i] = hi;
      lb[i] = bfhi(v - bff(hi));
    }
    u16* dh = vthi + ((size_t)(h * HID + j)) * NNODES + r0 + rh * 16;
    u16* dl = vtlo + ((size_t)(h * HID + j)) * NNODES + r0 + rh * 16;
    *(bf16x8*)dh = *(const bf16x8*)hb;
    *(bf16x8*)(dh + 8) = *(const bf16x8*)(hb + 8);
    *(bf16x8*)dl = *(const bf16x8*)lb;
    *(bf16x8*)(dl + 8) = *(const bf16x8*)(lb + 8);
  } else {
    u16* oh = (sel == 0 ? khi : qhi);
    u16* ol = (sel == 0 ? klo : qlo);
#pragma unroll
    for (int i = 0; i < 16; i++) {
      int row = r0 + rh * 16 + i;
      float v = acc[i];
      u16 hi = bfhi(v);
      oh[((size_t)h * NNODES + row) * HID + j] = hi;
      ol[((size_t)h * NNODES + row) * HID + j] = bfhi(v - bff(hi));
    }
  }
}

// ---------------------------------------------------------------------------
// MFMA flash attention, split-bf16 (3-term), KV-SPLIT over blockIdx.z.
// grid (4 heads, 64 q-tiles, NSPLIT kv-splits) = 768 blocks = 3 blocks/CU.
// Each split covers ~43 of 128 k-tiles; writes UNNORMALIZED partial U and
// per-row (m, l) for the merge in gate_kernel.
// ---------------------------------------------------------------------------
__global__ __launch_bounds__(256) void attn_kernel(
    const u16* __restrict__ qhi, const u16* __restrict__ qlo,
    const u16* __restrict__ khi, const u16* __restrict__ klo,
    const u16* __restrict__ vthi, const u16* __restrict__ vtlo,
    float* __restrict__ U, float* __restrict__ ml) {
  int h = blockIdx.x;
  int q0 = blockIdx.y * 64;
  int sp = blockIdx.z;
  int ktb = sp * 43;
  int kte = (sp == NSPLIT - 1) ? (NNODES / 32) : (ktb + 43);
  __shared__ __align__(16) u16 Kls[2][32 * 136];   // [hi/lo][node*136 + d]
  __shared__ __align__(16) u16 Vls[2][128 * 40];   // [hi/lo][d*40 + node]
  __shared__ __align__(16) u16 Pls[4][2][16 * 40]; // [wave][hi/lo][q*40 + node]
  int t = threadIdx.x;
  int w = t >> 6;
  int l = t & 63;
  int lr = l & 15;
  int lg = l >> 4;

  // Q fragments (A operand): row = lr, k = lg*8 + i, 4 chunks of K=32
  int qrow = q0 + w * 16 + lr;
  const u16* qbh = qhi + ((size_t)h * NNODES + qrow) * HID + lg * 8;
  const u16* qbl = qlo + ((size_t)h * NNODES + qrow) * HID + lg * 8;
  bf16x8 qfh[4], qfl[4];
#pragma unroll
  for (int c = 0; c < 4; c++) {
    qfh[c] = *(const bf16x8*)(qbh + c * 32);
    qfl[c] = *(const bf16x8*)(qbl + c * 32);
  }

  f32x4 out[8];
#pragma unroll
  for (int i = 0; i < 8; i++) out[i] = (f32x4){0.f, 0.f, 0.f, 0.f};
  float run_m[4], run_l[4];
#pragma unroll
  for (int r = 0; r < 4; r++) { run_m[r] = -1e30f; run_l[r] = 0.f; }

  const u16* kbh = khi + (size_t)h * NNODES * HID;
  const u16* kbl = klo + (size_t)h * NNODES * HID;
  const u16* vbh = vthi + (size_t)h * HID * NNODES;
  const u16* vbl = vtlo + (size_t)h * HID * NNODES;

  for (int kt = ktb; kt < kte; kt++) {
    // ---- stage K (row-major, pad 272B) and VT (d-major, pad 80B) ----
#pragma unroll
    for (int i = 0; i < 2; i++) {
      int flat = i * 256 + t;
      int node = flat >> 4, ch = flat & 15;
      *(bf16x8*)&Kls[0][node * 136 + ch * 8] =
          *(const bf16x8*)(kbh + ((size_t)(kt * 32 + node)) * HID + ch * 8);
      *(bf16x8*)&Kls[1][node * 136 + ch * 8] =
          *(const bf16x8*)(kbl + ((size_t)(kt * 32 + node)) * HID + ch * 8);
      int d = flat >> 2, c2 = flat & 3;
      *(bf16x8*)&Vls[0][d * 40 + c2 * 8] =
          *(const bf16x8*)(vbh + (size_t)d * NNODES + kt * 32 + c2 * 8);
      *(bf16x8*)&Vls[1][d * 40 + c2 * 8] =
          *(const bf16x8*)(vbl + (size_t)d * NNODES + kt * 32 + c2 * 8);
    }
    __syncthreads();

    // ---- QK^T: e(16q x 32k) = Q(16x128) K^T, 3-term split ----
    f32x4 ehh[2], ehl[2], elh[2];
#pragma unroll
    for (int ti = 0; ti < 2; ti++) {
      ehh[ti] = (f32x4){0.f, 0.f, 0.f, 0.f};
      ehl[ti] = (f32x4){0.f, 0.f, 0.f, 0.f};
      elh[ti] = (f32x4){0.f, 0.f, 0.f, 0.f};
    }
#pragma unroll
    for (int c = 0; c < 4; c++) {
#pragma unroll
      for (int ti = 0; ti < 2; ti++) {
        bf16x8 bh = *(const bf16x8*)&Kls[0][(ti * 16 + lr) * 136 + c * 32 + lg * 8];
        bf16x8 bl = *(const bf16x8*)&Kls[1][(ti * 16 + lr) * 136 + c * 32 + lg * 8];
        ehh[ti] = MFMA(qfh[c], bh, ehh[ti]);
        ehl[ti] = MFMA(qfh[c], bl, ehl[ti]);
        elh[ti] = MFMA(qfl[c], bh, elh[ti]);
      }
    }
    f32x4 e0 = ehh[0] + ehl[0] + elh[0];
    f32x4 e1 = ehh[1] + ehl[1] + elh[1];

    // ---- online softmax (rows live in lane groups; reduce over lr) ----
    float sc[4];
#pragma unroll
    for (int r = 0; r < 4; r++) {
      float m2 = fmaxf(e0[r], e1[r]);
      m2 = fmaxf(m2, __shfl_xor(m2, 1));
      m2 = fmaxf(m2, __shfl_xor(m2, 2));
      m2 = fmaxf(m2, __shfl_xor(m2, 4));
      m2 = fmaxf(m2, __shfl_xor(m2, 8));
      float nm = fmaxf(run_m[r], m2);
      sc[r] = __expf(run_m[r] - nm);
      run_m[r] = nm;
      float p0 = __expf(e0[r] - nm);
      float p1 = __expf(e1[r] - nm);
      float lt = p0 + p1;
      lt += __shfl_xor(lt, 1);
      lt += __shfl_xor(lt, 2);
      lt += __shfl_xor(lt, 4);
      lt += __shfl_xor(lt, 8);
      run_l[r] = run_l[r] * sc[r] + lt;
      int prow = 4 * lg + r;
      u16 p0h = bfhi(p0);
      u16 p1h = bfhi(p1);
      Pls[w][0][prow * 40 + lr] = p0h;
      Pls[w][0][prow * 40 + 16 + lr] = p1h;
      Pls[w][1][prow * 40 + lr] = bfhi(p0 - bff(p0h));
      Pls[w][1][prow * 40 + 16 + lr] = bfhi(p1 - bff(p1h));
    }
#pragma unroll
    for (int dt = 0; dt < 8; dt++) {
      out[dt][0] *= sc[0];
      out[dt][1] *= sc[1];
      out[dt][2] *= sc[2];
      out[dt][3] *= sc[3];
    }

    // ---- PV: out(16q x 128d) += P(16x32) V(32x128), 3-term split ----
    bf16x8 ah = *(const bf16x8*)&Pls[w][0][lr * 40 + lg * 8];
    bf16x8 al = *(const bf16x8*)&Pls[w][1][lr * 40 + lg * 8];
#pragma unroll
    for (int dt = 0; dt < 8; dt++) {
      bf16x8 bh = *(const bf16x8*)&Vls[0][(dt * 16 + lr) * 40 + lg * 8];
      bf16x8 bl = *(const bf16x8*)&Vls[1][(dt * 16 + lr) * 40 + lg * 8];
      out[dt] = MFMA(ah, bh, out[dt]);
      out[dt] = MFMA(ah, bl, out[dt]);
      out[dt] = MFMA(al, bh, out[dt]);
    }
    __syncthreads();
  }

  // ---- epilogue: write UNNORMALIZED partial U and per-row (m, l) ----
  float* ob = U + (((size_t)(sp * 4 + h) * NNODES) + q0 + w * 16) * HID;
#pragma unroll
  for (int dt = 0; dt < 8; dt++)
#pragma unroll
    for (int r = 0; r < 4; r++)
      ob[(size_t)(4 * lg + r) * HID + dt * 16 + lr] = out[dt][r];
  if (lr == 0) {
#pragma unroll
    for (int r = 0; r < 4; r++) {
      size_t mi = (((size_t)(sp * 4 + h) * NNODES) + q0 + w * 16 + 4 * lg + r) * 2;
      ml[mi] = run_m[r];
      ml[mi + 1] = run_l[r];
    }
  }
}

// ---------------------------------------------------------------------------
// Gating + KV-split merge:
// x = x + relu((x + sum_h Wm[h] * merge_s(U[s][h], m, l)) @ Wg + bg)
// merge coefs per (row, h): coef[s] = exp(m_s - M) / sum_s l_s*exp(m_s - M)
// ---------------------------------------------------------------------------
__global__ __launch_bounds__(256) void gate_kernel(
    float* __restrict__ x, const float* __restrict__ U,
    const float* __restrict__ ml,
    const float* __restrict__ Wm, const float* __restrict__ Wg,
    const float* __restrict__ bg) {
  int r0 = blockIdx.x * 32;
  __shared__ float ss[32][132];
  __shared__ float cs[32][4][NSPLIT];  // Wm[h]*coef per (row, head, split)
  int t = threadIdx.x;
  if (t < 128) {
    int r = t >> 2, h = t & 3;
    int row = r0 + r;
    float ms[NSPLIT], ls[NSPLIT];
#pragma unroll
    for (int s = 0; s < NSPLIT; s++) {
      size_t mi = (((size_t)(s * 4 + h) * NNODES) + row) * 2;
      ms[s] = ml[mi];
      ls[s] = ml[mi + 1];
    }
    float M = fmaxf(fmaxf(ms[0], ms[1]), ms[2]);
    float w0 = __expf(ms[0] - M), w1 = __expf(ms[1] - M), w2 = __expf(ms[2] - M);
    float denom = ls[0] * w0 + ls[1] * w1 + ls[2] * w2;
    float wmh = Wm[h] / denom;
    cs[r][h][0] = w0 * wmh;
    cs[r][h][1] = w1 * wmh;
    cs[r][h][2] = w2 * wmh;
  }
  __syncthreads();
  for (int i = t; i < 32 * 32; i += 256) {
    int r = i >> 5, c = (i & 31) * 4;
    size_t off = (size_t)(r0 + r) * HID + c;
    float4 s = *(const float4*)(x + off);
#pragma unroll
    for (int h = 0; h < 4; h++) {
#pragma unroll
      for (int sp = 0; sp < NSPLIT; sp++) {
        float cc = cs[r][h][sp];
        float4 u = *(const float4*)(U + (size_t)(sp * 4 + h) * NNODES * HID + off);
        s.x = fmaf(cc, u.x, s.x);
        s.y = fmaf(cc, u.y, s.y);
        s.z = fmaf(cc, u.z, s.z);
        s.w = fmaf(cc, u.w, s.w);
      }
    }
    *(float4*)&ss[r][c] = s;
  }
  __syncthreads();
  int j = t & 127;
  int rh = t >> 7;
  float acc[16];
#pragma unroll
  for (int i = 0; i < 16; i++) acc[i] = bg[j];
  for (int d = 0; d < HID; d += 4) {
    float w0 = Wg[(d + 0) * HID + j];
    float w1 = Wg[(d + 1) * HID + j];
    float w2 = Wg[(d + 2) * HID + j];
    float w3 = Wg[(d + 3) * HID + j];
#pragma unroll
    for (int i = 0; i < 16; i++) {
      float4 sv = *(const float4*)&ss[rh * 16 + i][d];
      acc[i] = fmaf(sv.x, w0, fmaf(sv.y, w1, fmaf(sv.z, w2, fmaf(sv.w, w3, acc[i]))));
    }
  }
#pragma unroll
  for (int i = 0; i < 16; i++) {
    size_t r = (size_t)(r0 + rh * 16 + i) * HID + j;
    x[r] = x[r] + fmaxf(acc[i], 0.f);
  }
}

// ---------------------------------------------------------------------------
__global__ __launch_bounds__(128) void colsum_kernel(const float* __restrict__ x,
                                                     float* __restrict__ xsum) {
  int j = threadIdx.x;
  int r0 = blockIdx.x * 32;
  float s = 0.f;
  for (int r = 0; r < 32; r++) s += x[(size_t)(r0 + r) * HID + j];
  atomicAdd(&xsum[j], s);
}

__global__ __launch_bounds__(128) void ground_kernel(
    const float* __restrict__ x, const float* __restrict__ xsum,
    const float* __restrict__ Wglob, const float* __restrict__ bglob,
    const float* __restrict__ Wgr, const float* __restrict__ bgr,
    float* __restrict__ G, float* __restrict__ dout) {
  __shared__ float xm[128];
  __shared__ float Gs[128];
  int j = threadIdx.x;
  xm[j] = xsum[j] * (1.f / 4096.f);
  __syncthreads();
  float acc = bglob[j];
  for (int d = 0; d < 128; d++) acc += xm[d] * Wglob[d * 128 + j];
  G[j] = acc;
  Gs[j] = acc;
  __syncthreads();
  if (j < 8) {
    float a = bgr[j];
    for (int d = 0; d < 128; d++) a += x[d] * Wgr[d * 8 + j];
    for (int d = 0; d < 128; d++) a += Gs[d] * Wgr[(128 + d) * 8 + j];
    dout[j] = a;
  }
}

__global__ __launch_bounds__(256) void qblocks_kernel(
    const float* __restrict__ x, const float* __restrict__ G,
    const float* __restrict__ Wd, const float* __restrict__ bd,
    float* __restrict__ dout) {
  int r0 = blockIdx.x * 32;
  int tt = r0 >> 9;
  __shared__ float xs[32][132];
  __shared__ float Gs[128];
  int t = threadIdx.x;
  if (t < 128) Gs[t] = G[t];
  for (int i = t; i < 32 * 32; i += 256) {
    int r = i >> 5, c = (i & 31) * 4;
    *(float4*)&xs[r][c] = *(const float4*)(x + (size_t)(1 + r0 + r) * HID + c);
  }
  __syncthreads();
  int r = t >> 3, a = t & 7;
  const float* Wt = Wd + (size_t)tt * 256 * 8;
  float acc = bd[tt * 8 + a];
  for (int d = 0; d < 128; d++) acc += xs[r][d] * Wt[d * 8 + a];
  for (int d = 0; d < 128; d++) acc += Gs[d] * Wt[(128 + d) * 8 + a];
  dout[8 + (size_t)(r0 + r) * 8 + a] = acc;
}

// ---------------------------------------------------------------------------
extern "C" void kernel_launch(void* const* d_in, const int* in_sizes, int n_in,
                              void* d_out, int out_size, void* d_ws, size_t ws_size,
                              hipStream_t stream) {
  const float* blocks    = (const float*)d_in[0];
  const float* obstacles = (const float*)d_in[1];
  const float* targets   = (const float*)d_in[2];
  const float* Wb1 = (const float*)d_in[3];
  const float* bb1 = (const float*)d_in[4];
  const float* Wb2 = (const float*)d_in[5];
  const float* bb2 = (const float*)d_in[6];
  const float* Wd  = (const float*)d_in[7];
  const float* bd  = (const float*)d_in[8];
  const float* Wo1 = (const float*)d_in[9];
  const float* bo1 = (const float*)d_in[10];
  const float* Wo2 = (const float*)d_in[11];
  const float* bo2 = (const float*)d_in[12];
  const float* Wt1 = (const float*)d_in[13];
  const float* bt1 = (const float*)d_in[14];
  const float* Wt2 = (const float*)d_in[15];
  const float* bt2 = (const float*)d_in[16];
  const float* ground = (const float*)d_in[17];
  const float* Wk = (const float*)d_in[18];
  const float* Wq = (const float*)d_in[19];
  const float* Wv = (const float*)d_in[20];
  const float* Wm = (const float*)d_in[21];
  const float* Wg = (const float*)d_in[22];
  const float* bg = (const float*)d_in[23];
  const float* Wglob = (const float*)d_in[24];
  const float* bglob = (const float*)d_in[25];
  const float* Wgr = (const float*)d_in[26];
  const float* bgr = (const float*)d_in[27];

  float* ws = (float*)d_ws;
  float* x    = ws;                          // 524288 f32
  float* U    = x + 524288;                  // NSPLIT*4*4096*128 = 6291456 f32
  float* ml   = U + (size_t)NSPLIT * 4 * NNODES * HID;  // 98304 f32
  float* xsum = ml + (size_t)NSPLIT * 4 * NNODES * 2;   // 128
  float* G    = xsum + 128;                  // 128
  u16* qhi  = (u16*)(G + 128);               // each 2097152 u16 (4 MB)
  u16* qlo  = qhi + 2097152;
  u16* khi  = qlo + 2097152;
  u16* klo  = khi + 2097152;
  u16* vthi = klo + 2097152;
  u16* vtlo = vthi + 2097152;
  float* dout = (float*)d_out;

  encode_kernel<<<NNODES, 128, 0, stream>>>(
      blocks, obstacles, targets, Wb1, bb1, Wb2, bb2, Wo1, bo1, Wo2, bo2,
      Wt1, bt1, Wt2, bt2, ground, x);

  for (int round = 0; round < 3; round++) {
    qkv_kernel<<<dim3(12, NNODES / 32), 256, 0, stream>>>(
        x, Wk, Wq, Wv, khi, klo, qhi, qlo, vthi, vtlo);
    attn_kernel<<<dim3(4, NNODES / 64, NSPLIT), 256, 0, stream>>>(
        qhi, qlo, khi, klo, vthi, vtlo, U, ml);
    gate_kernel<<<NNODES / 32, 256, 0, stream>>>(x, U, ml, Wm, Wg, bg);
  }

  hipMemsetAsync(xsum, 0, 128 * sizeof(float), stream);
  colsum_kernel<<<NNODES / 32, 128, 0, stream>>>(x, xsum);
  ground_kernel<<<1, 128, 0, stream>>>(x, xsum, Wglob, bglob, Wgr, bgr, G, dout);
  qblocks_kernel<<<64, 256, 0, stream>>>(x, G, Wd, bd, dout);
}

// Round 11
// 858.084 us; speedup vs baseline: 4.3921x; 1.0113x over previous
//
#include <hip/hip_runtime.h>

#define HID 128
#define NNODES 4096
#define T 4
#define N_PER 512
#define NSPLIT 3

typedef unsigned short u16;
typedef __attribute__((ext_vector_type(8))) short bf16x8;
typedef __attribute__((ext_vector_type(4))) float f32x4;

#define MFMA(a, b, c) __builtin_amdgcn_mfma_f32_16x16x32_bf16((a), (b), (c), 0, 0, 0)

__device__ __forceinline__ u16 bfhi(float f) {
  union { float f; unsigned u; } v; v.f = f;
  return (u16)(v.u >> 16);
}
__device__ __forceinline__ float bff(u16 h) {
  union { float f; unsigned u; } v; v.u = ((unsigned)h) << 16;
  return v.f;
}

// ---------------------------------------------------------------------------
// Pre-split Wk/Wq/Wv into TRANSPOSED bf16 hi/lo: wt[m][col][k], m = sel*4+h.
// B-fragment reads become contiguous 16B along k.
// ---------------------------------------------------------------------------
__global__ __launch_bounds__(256) void presplit_kernel(
    const float* __restrict__ Wk, const float* __restrict__ Wq,
    const float* __restrict__ Wv,
    u16* __restrict__ wthi, u16* __restrict__ wtlo) {
  int t = blockIdx.x * 256 + threadIdx.x;  // 0..196607
  int m = t >> 14;
  int rem = t & 16383;
  int k = rem >> 7, col = rem & 127;
  int h = m & 3, sel = m >> 2;
  const float* W = (sel == 0 ? Wk : (sel == 1 ? Wq : Wv)) + (size_t)h * HID * HID;
  float v = W[k * HID + col];
  u16 hi = bfhi(v);
  size_t o = (size_t)m * 16384 + col * 128 + k;
  wthi[o] = hi;
  wtlo[o] = bfhi(v - bff(hi));
}

// ---------------------------------------------------------------------------
// Encoders: build x[4096][128] fp32 + split bf16 (xhi/xlo) for MFMA consumers
// ---------------------------------------------------------------------------
__global__ __launch_bounds__(128) void encode_kernel(
    const float* __restrict__ blocks, const float* __restrict__ obstacles,
    const float* __restrict__ targets,
    const float* __restrict__ Wb1, const float* __restrict__ bb1,
    const float* __restrict__ Wb2, const float* __restrict__ bb2,
    const float* __restrict__ Wo1, const float* __restrict__ bo1,
    const float* __restrict__ Wo2, const float* __restrict__ bo2,
    const float* __restrict__ Wt1, const float* __restrict__ bt1,
    const float* __restrict__ Wt2, const float* __restrict__ bt2,
    const float* __restrict__ ground, float* __restrict__ x,
    u16* __restrict__ xhi, u16* __restrict__ xlo) {
  int n = blockIdx.x;
  int j = threadIdx.x;
  __shared__ float in_s[32];
  __shared__ float h_s[128];
  if (n == 0) {
    float g = ground[j];
    x[j] = g;
    u16 hi = bfhi(g);
    xhi[j] = hi;
    xlo[j] = bfhi(g - bff(hi));
    return;
  }
  const float *W1, *b1, *W2, *b2, *inp;
  int D;
  if (n <= 2048) {
    int b = n - 1;
    int t = b >> 9;
    inp = blocks + (size_t)b * 33;
    D = 32;
    W1 = Wb1 + (size_t)t * 32 * HID;
    b1 = bb1 + (size_t)t * HID;
    W2 = Wb2 + (size_t)t * HID * HID;
    b2 = bb2 + (size_t)t * HID;
  } else if (n <= 3072) {
    int o = n - 2049;
    inp = obstacles + (size_t)o * 16;
    D = 16;
    W1 = Wo1; b1 = bo1; W2 = Wo2; b2 = bo2;
  } else {
    int tg = n - 3073;
    inp = targets + (size_t)tg * 16;
    D = 16;
    W1 = Wt1; b1 = bt1; W2 = Wt2; b2 = bt2;
  }
  if (j < D) in_s[j] = inp[j];
  __syncthreads();
  float acc = b1[j];
  for (int d = 0; d < D; d++) acc += in_s[d] * W1[d * HID + j];
  h_s[j] = fmaxf(acc, 0.f);
  __syncthreads();
  float acc2 = b2[j];
  for (int k = 0; k < HID; k++) acc2 += h_s[k] * W2[k * HID + j];
  size_t o = (size_t)n * HID + j;
  x[o] = acc2;
  u16 hi = bfhi(acc2);
  xhi[o] = hi;
  xlo[o] = bfhi(acc2 - bff(hi));
}

// ---------------------------------------------------------------------------
// MFMA QKV: OUT = X @ W[m], 3-term split-bf16, NO LDS (X, wT are L2-hot).
// grid (12 mat-heads, 256 row-tiles) x 64 threads (1 wave, 16 rows).
// A: row=l&15, k=(l>>4)*8+i (from xhi/xlo); B: col=l&15, same k (from wT).
// C: col=l&15, row=(l>>4)*4+reg.
// ---------------------------------------------------------------------------
__global__ __launch_bounds__(64) void qkv_kernel(
    const u16* __restrict__ xhi, const u16* __restrict__ xlo,
    const u16* __restrict__ wthi, const u16* __restrict__ wtlo,
    u16* __restrict__ khi, u16* __restrict__ klo,
    u16* __restrict__ qhi, u16* __restrict__ qlo,
    u16* __restrict__ vthi, u16* __restrict__ vtlo) {
  int m = blockIdx.x;
  int h = m & 3, sel = m >> 2;
  int r0 = blockIdx.y * 16;
  int l = threadIdx.x;
  int lr = l & 15, lg = l >> 4;
  const u16* wh = wthi + (size_t)m * 16384;
  const u16* wl = wtlo + (size_t)m * 16384;
  f32x4 acc[8];
#pragma unroll
  for (int i = 0; i < 8; i++) acc[i] = (f32x4){0.f, 0.f, 0.f, 0.f};
#pragma unroll
  for (int c = 0; c < 4; c++) {
    bf16x8 ah = *(const bf16x8*)(xhi + (size_t)(r0 + lr) * HID + c * 32 + lg * 8);
    bf16x8 al = *(const bf16x8*)(xlo + (size_t)(r0 + lr) * HID + c * 32 + lg * 8);
#pragma unroll
    for (int dt = 0; dt < 8; dt++) {
      bf16x8 bh = *(const bf16x8*)(wh + (dt * 16 + lr) * 128 + c * 32 + lg * 8);
      bf16x8 bl = *(const bf16x8*)(wl + (dt * 16 + lr) * 128 + c * 32 + lg * 8);
      acc[dt] = MFMA(ah, bh, acc[dt]);
      acc[dt] = MFMA(ah, bl, acc[dt]);
      acc[dt] = MFMA(al, bh, acc[dt]);
    }
  }
  if (sel == 2) {
#pragma unroll
    for (int dt = 0; dt < 8; dt++)
#pragma unroll
      for (int r = 0; r < 4; r++) {
        int row = r0 + 4 * lg + r, col = dt * 16 + lr;
        float v = acc[dt][r];
        u16 hi = bfhi(v);
        size_t o = ((size_t)h * HID + col) * NNODES + row;
        vthi[o] = hi;
        vtlo[o] = bfhi(v - bff(hi));
      }
  } else {
    u16* oh = (sel == 0 ? khi : qhi);
    u16* ol = (sel == 0 ? klo : qlo);
#pragma unroll
    for (int dt = 0; dt < 8; dt++)
#pragma unroll
      for (int r = 0; r < 4; r++) {
        int row = r0 + 4 * lg + r, col = dt * 16 + lr;
        float v = acc[dt][r];
        u16 hi = bfhi(v);
        size_t o = ((size_t)h * NNODES + row) * HID + col;
        oh[o] = hi;
        ol[o] = bfhi(v - bff(hi));
      }
  }
}

// ---------------------------------------------------------------------------
// MFMA flash attention, split-bf16 (3-term) QK^T AND PV (validated round-5
// structure — single-term PV FAILED absmax 5.68, round-10 post-mortem).
// KV-split over blockIdx.z, NSPLIT=3 -> 768 blocks = 3 blocks/CU @48KB LDS.
// ---------------------------------------------------------------------------
__global__ __launch_bounds__(256) void attn_kernel(
    const u16* __restrict__ qhi, const u16* __restrict__ qlo,
    const u16* __restrict__ khi, const u16* __restrict__ klo,
    const u16* __restrict__ vthi, const u16* __restrict__ vtlo,
    float* __restrict__ U, float* __restrict__ ml) {
  int h = blockIdx.x;
  int q0 = blockIdx.y * 64;
  int sp = blockIdx.z;
  int ktb = sp * 43;
  int kte = (sp == NSPLIT - 1) ? (NNODES / 32) : (ktb + 43);
  __shared__ __align__(16) u16 Kls[2][32 * 136];   // [hi/lo][node*136 + d]
  __shared__ __align__(16) u16 Vls[2][128 * 40];   // [hi/lo][d*40 + node]
  __shared__ __align__(16) u16 Pls[4][2][16 * 40]; // [wave][hi/lo][q*40 + node]
  int t = threadIdx.x;
  int w = t >> 6;
  int l = t & 63;
  int lr = l & 15;
  int lg = l >> 4;

  int qrow = q0 + w * 16 + lr;
  const u16* qbh = qhi + ((size_t)h * NNODES + qrow) * HID + lg * 8;
  const u16* qbl = qlo + ((size_t)h * NNODES + qrow) * HID + lg * 8;
  bf16x8 qfh[4], qfl[4];
#pragma unroll
  for (int c = 0; c < 4; c++) {
    qfh[c] = *(const bf16x8*)(qbh + c * 32);
    qfl[c] = *(const bf16x8*)(qbl + c * 32);
  }

  f32x4 out[8];
#pragma unroll
  for (int i = 0; i < 8; i++) out[i] = (f32x4){0.f, 0.f, 0.f, 0.f};
  float run_m[4], run_l[4];
#pragma unroll
  for (int r = 0; r < 4; r++) { run_m[r] = -1e30f; run_l[r] = 0.f; }

  const u16* kbh = khi + (size_t)h * NNODES * HID;
  const u16* kbl = klo + (size_t)h * NNODES * HID;
  const u16* vbh = vthi + (size_t)h * HID * NNODES;
  const u16* vbl = vtlo + (size_t)h * HID * NNODES;

  for (int kt = ktb; kt < kte; kt++) {
#pragma unroll
    for (int i = 0; i < 2; i++) {
      int flat = i * 256 + t;
      int node = flat >> 4, ch = flat & 15;
      *(bf16x8*)&Kls[0][node * 136 + ch * 8] =
          *(const bf16x8*)(kbh + ((size_t)(kt * 32 + node)) * HID + ch * 8);
      *(bf16x8*)&Kls[1][node * 136 + ch * 8] =
          *(const bf16x8*)(kbl + ((size_t)(kt * 32 + node)) * HID + ch * 8);
      int d = flat >> 2, c2 = flat & 3;
      *(bf16x8*)&Vls[0][d * 40 + c2 * 8] =
          *(const bf16x8*)(vbh + (size_t)d * NNODES + kt * 32 + c2 * 8);
      *(bf16x8*)&Vls[1][d * 40 + c2 * 8] =
          *(const bf16x8*)(vbl + (size_t)d * NNODES + kt * 32 + c2 * 8);
    }
    __syncthreads();

    f32x4 ehh[2], ehl[2], elh[2];
#pragma unroll
    for (int ti = 0; ti < 2; ti++) {
      ehh[ti] = (f32x4){0.f, 0.f, 0.f, 0.f};
      ehl[ti] = (f32x4){0.f, 0.f, 0.f, 0.f};
      elh[ti] = (f32x4){0.f, 0.f, 0.f, 0.f};
    }
#pragma unroll
    for (int c = 0; c < 4; c++) {
#pragma unroll
      for (int ti = 0; ti < 2; ti++) {
        bf16x8 bh = *(const bf16x8*)&Kls[0][(ti * 16 + lr) * 136 + c * 32 + lg * 8];
        bf16x8 bl = *(const bf16x8*)&Kls[1][(ti * 16 + lr) * 136 + c * 32 + lg * 8];
        ehh[ti] = MFMA(qfh[c], bh, ehh[ti]);
        ehl[ti] = MFMA(qfh[c], bl, ehl[ti]);
        elh[ti] = MFMA(qfl[c], bh, elh[ti]);
      }
    }
    f32x4 e0 = ehh[0] + ehl[0] + elh[0];
    f32x4 e1 = ehh[1] + ehl[1] + elh[1];

    float sc[4];
#pragma unroll
    for (int r = 0; r < 4; r++) {
      float m2 = fmaxf(e0[r], e1[r]);
      m2 = fmaxf(m2, __shfl_xor(m2, 1));
      m2 = fmaxf(m2, __shfl_xor(m2, 2));
      m2 = fmaxf(m2, __shfl_xor(m2, 4));
      m2 = fmaxf(m2, __shfl_xor(m2, 8));
      float nm = fmaxf(run_m[r], m2);
      sc[r] = __expf(run_m[r] - nm);
      run_m[r] = nm;
      float p0 = __expf(e0[r] - nm);
      float p1 = __expf(e1[r] - nm);
      float lt = p0 + p1;
      lt += __shfl_xor(lt, 1);
      lt += __shfl_xor(lt, 2);
      lt += __shfl_xor(lt, 4);
      lt += __shfl_xor(lt, 8);
      run_l[r] = run_l[r] * sc[r] + lt;
      int prow = 4 * lg + r;
      u16 p0h = bfhi(p0);
      u16 p1h = bfhi(p1);
      Pls[w][0][prow * 40 + lr] = p0h;
      Pls[w][0][prow * 40 + 16 + lr] = p1h;
      Pls[w][1][prow * 40 + lr] = bfhi(p0 - bff(p0h));
      Pls[w][1][prow * 40 + 16 + lr] = bfhi(p1 - bff(p1h));
    }
#pragma unroll
    for (int dt = 0; dt < 8; dt++) {
      out[dt][0] *= sc[0];
      out[dt][1] *= sc[1];
      out[dt][2] *= sc[2];
      out[dt][3] *= sc[3];
    }

    bf16x8 ah = *(const bf16x8*)&Pls[w][0][lr * 40 + lg * 8];
    bf16x8 al = *(const bf16x8*)&Pls[w][1][lr * 40 + lg * 8];
#pragma unroll
    for (int dt = 0; dt < 8; dt++) {
      bf16x8 bh = *(const bf16x8*)&Vls[0][(dt * 16 + lr) * 40 + lg * 8];
      bf16x8 bl = *(const bf16x8*)&Vls[1][(dt * 16 + lr) * 40 + lg * 8];
      out[dt] = MFMA(ah, bh, out[dt]);
      out[dt] = MFMA(ah, bl, out[dt]);
      out[dt] = MFMA(al, bh, out[dt]);
    }
    __syncthreads();
  }

  float* ob = U + (((size_t)(sp * 4 + h) * NNODES) + q0 + w * 16) * HID;
#pragma unroll
  for (int dt = 0; dt < 8; dt++)
#pragma unroll
    for (int r = 0; r < 4; r++)
      ob[(size_t)(4 * lg + r) * HID + dt * 16 + lr] = out[dt][r];
  if (lr == 0) {
#pragma unroll
    for (int r = 0; r < 4; r++) {
      size_t mi = (((size_t)(sp * 4 + h) * NNODES) + q0 + w * 16 + 4 * lg + r) * 2;
      ml[mi] = run_m[r];
      ml[mi + 1] = run_l[r];
    }
  }
}

// ---------------------------------------------------------------------------
// Gating + KV-split merge; also re-emits x as split bf16 for next round's qkv
// ---------------------------------------------------------------------------
__global__ __launch_bounds__(256) void gate_kernel(
    float* __restrict__ x, const float* __restrict__ U,
    const float* __restrict__ ml,
    const float* __restrict__ Wm, const float* __restrict__ Wg,
    const float* __restrict__ bg,
    u16* __restrict__ xhi, u16* __restrict__ xlo) {
  int r0 = blockIdx.x * 32;
  __shared__ float ss[32][132];
  __shared__ float cs[32][4][NSPLIT];
  int t = threadIdx.x;
  if (t < 128) {
    int r = t >> 2, h = t & 3;
    int row = r0 + r;
    float ms[NSPLIT], ls[NSPLIT];
#pragma unroll
    for (int s = 0; s < NSPLIT; s++) {
      size_t mi = (((size_t)(s * 4 + h) * NNODES) + row) * 2;
      ms[s] = ml[mi];
      ls[s] = ml[mi + 1];
    }
    float M = fmaxf(fmaxf(ms[0], ms[1]), ms[2]);
    float w0 = __expf(ms[0] - M), w1 = __expf(ms[1] - M), w2 = __expf(ms[2] - M);
    float denom = ls[0] * w0 + ls[1] * w1 + ls[2] * w2;
    float wmh = Wm[h] / denom;
    cs[r][h][0] = w0 * wmh;
    cs[r][h][1] = w1 * wmh;
    cs[r][h][2] = w2 * wmh;
  }
  __syncthreads();
  for (int i = t; i < 32 * 32; i += 256) {
    int r = i >> 5, c = (i & 31) * 4;
    size_t off = (size_t)(r0 + r) * HID + c;
    float4 s = *(const float4*)(x + off);
#pragma unroll
    for (int h = 0; h < 4; h++) {
#pragma unroll
      for (int sp = 0; sp < NSPLIT; sp++) {
        float cc = cs[r][h][sp];
        float4 u = *(const float4*)(U + (size_t)(sp * 4 + h) * NNODES * HID + off);
        s.x = fmaf(cc, u.x, s.x);
        s.y = fmaf(cc, u.y, s.y);
        s.z = fmaf(cc, u.z, s.z);
        s.w = fmaf(cc, u.w, s.w);
      }
    }
    *(float4*)&ss[r][c] = s;
  }
  __syncthreads();
  int j = t & 127;
  int rh = t >> 7;
  float acc[16];
#pragma unroll
  for (int i = 0; i < 16; i++) acc[i] = bg[j];
  for (int d = 0; d < HID; d += 4) {
    float w0 = Wg[(d + 0) * HID + j];
    float w1 = Wg[(d + 1) * HID + j];
    float w2 = Wg[(d + 2) * HID + j];
    float w3 = Wg[(d + 3) * HID + j];
#pragma unroll
    for (int i = 0; i < 16; i++) {
      float4 sv = *(const float4*)&ss[rh * 16 + i][d];
      acc[i] = fmaf(sv.x, w0, fmaf(sv.y, w1, fmaf(sv.z, w2, fmaf(sv.w, w3, acc[i]))));
    }
  }
#pragma unroll
  for (int i = 0; i < 16; i++) {
    size_t r = (size_t)(r0 + rh * 16 + i) * HID + j;
    float nv = x[r] + fmaxf(acc[i], 0.f);
    x[r] = nv;
    u16 hi = bfhi(nv);
    xhi[r] = hi;
    xlo[r] = bfhi(nv - bff(hi));
  }
}

// ---------------------------------------------------------------------------
__global__ __launch_bounds__(128) void colsum_kernel(const float* __restrict__ x,
                                                     float* __restrict__ xsum) {
  int j = threadIdx.x;
  int r0 = blockIdx.x * 32;
  float s = 0.f;
  for (int r = 0; r < 32; r++) s += x[(size_t)(r0 + r) * HID + j];
  atomicAdd(&xsum[j], s);
}

__global__ __launch_bounds__(128) void ground_kernel(
    const float* __restrict__ x, const float* __restrict__ xsum,
    const float* __restrict__ Wglob, const float* __restrict__ bglob,
    const float* __restrict__ Wgr, const float* __restrict__ bgr,
    float* __restrict__ G, float* __restrict__ dout) {
  __shared__ float xm[128];
  __shared__ float Gs[128];
  int j = threadIdx.x;
  xm[j] = xsum[j] * (1.f / 4096.f);
  __syncthreads();
  float acc = bglob[j];
  for (int d = 0; d < 128; d++) acc += xm[d] * Wglob[d * 128 + j];
  G[j] = acc;
  Gs[j] = acc;
  __syncthreads();
  if (j < 8) {
    float a = bgr[j];
    for (int d = 0; d < 128; d++) a += x[d] * Wgr[d * 8 + j];
    for (int d = 0; d < 128; d++) a += Gs[d] * Wgr[(128 + d) * 8 + j];
    dout[j] = a;
  }
}

__global__ __launch_bounds__(256) void qblocks_kernel(
    const float* __restrict__ x, const float* __restrict__ G,
    const float* __restrict__ Wd, const float* __restrict__ bd,
    float* __restrict__ dout) {
  int r0 = blockIdx.x * 32;
  int tt = r0 >> 9;
  __shared__ float xs[32][132];
  __shared__ float Gs[128];
  int t = threadIdx.x;
  if (t < 128) Gs[t] = G[t];
  for (int i = t; i < 32 * 32; i += 256) {
    int r = i >> 5, c = (i & 31) * 4;
    *(float4*)&xs[r][c] = *(const float4*)(x + (size_t)(1 + r0 + r) * HID + c);
  }
  __syncthreads();
  int r = t >> 3, a = t & 7;
  const float* Wt = Wd + (size_t)tt * 256 * 8;
  float acc = bd[tt * 8 + a];
  for (int d = 0; d < 128; d++) acc += xs[r][d] * Wt[d * 8 + a];
  for (int d = 0; d < 128; d++) acc += Gs[d] * Wt[(128 + d) * 8 + a];
  dout[8 + (size_t)(r0 + r) * 8 + a] = acc;
}

// ---------------------------------------------------------------------------
extern "C" void kernel_launch(void* const* d_in, const int* in_sizes, int n_in,
                              void* d_out, int out_size, void* d_ws, size_t ws_size,
                              hipStream_t stream) {
  const float* blocks    = (const float*)d_in[0];
  const float* obstacles = (const float*)d_in[1];
  const float* targets   = (const float*)d_in[2];
  const float* Wb1 = (const float*)d_in[3];
  const float* bb1 = (const float*)d_in[4];
  const float* Wb2 = (const float*)d_in[5];
  const float* bb2 = (const float*)d_in[6];
  const float* Wd  = (const float*)d_in[7];
  const float* bd  = (const float*)d_in[8];
  const float* Wo1 = (const float*)d_in[9];
  const float* bo1 = (const float*)d_in[10];
  const float* Wo2 = (const float*)d_in[11];
  const float* bo2 = (const float*)d_in[12];
  const float* Wt1 = (const float*)d_in[13];
  const float* bt1 = (const float*)d_in[14];
  const float* Wt2 = (const float*)d_in[15];
  const float* bt2 = (const float*)d_in[16];
  const float* ground = (const float*)d_in[17];
  const float* Wk = (const float*)d_in[18];
  const float* Wq = (const float*)d_in[19];
  const float* Wv = (const float*)d_in[20];
  const float* Wm = (const float*)d_in[21];
  const float* Wg = (const float*)d_in[22];
  const float* bg = (const float*)d_in[23];
  const float* Wglob = (const float*)d_in[24];
  const float* bglob = (const float*)d_in[25];
  const float* Wgr = (const float*)d_in[26];
  const float* bgr = (const float*)d_in[27];

  float* ws = (float*)d_ws;
  float* x    = ws;                          // 524288 f32
  float* U    = x + 524288;                  // 3*4*4096*128 = 6291456 f32
  float* ml   = U + 6291456;                 // 98304 f32
  float* xsum = ml + 98304;                  // 128
  float* G    = xsum + 128;                  // 128
  u16* qhi  = (u16*)(G + 128);               // each 2097152 u16 (4 MB)
  u16* qlo  = qhi + 2097152;
  u16* khi  = qlo + 2097152;
  u16* klo  = khi + 2097152;
  u16* vthi = klo + 2097152;
  u16* vtlo = vthi + 2097152;
  u16* xhi  = vtlo + 2097152;                // 524288 u16
  u16* xlo  = xhi + 524288;                  // 524288 u16
  u16* wthi = xlo + 524288;                  // 196608 u16
  u16* wtlo = wthi + 196608;                 // 196608 u16
  float* dout = (float*)d_out;

  presplit_kernel<<<768, 256, 0, stream>>>(Wk, Wq, Wv, wthi, wtlo);
  encode_kernel<<<NNODES, 128, 0, stream>>>(
      blocks, obstacles, targets, Wb1, bb1, Wb2, bb2, Wo1, bo1, Wo2, bo2,
      Wt1, bt1, Wt2, bt2, ground, x, xhi, xlo);

  for (int round = 0; round < 3; round++) {
    qkv_kernel<<<dim3(12, NNODES / 16), 64, 0, stream>>>(
        xhi, xlo, wthi, wtlo, khi, klo, qhi, qlo, vthi, vtlo);
    attn_kernel<<<dim3(4, NNODES / 64, NSPLIT), 256, 0, stream>>>(
        qhi, qlo, khi, klo, vthi, vtlo, U, ml);
    gate_kernel<<<NNODES / 32, 256, 0, stream>>>(x, U, ml, Wm, Wg, bg, xhi, xlo);
  }

  hipMemsetAsync(xsum, 0, 128 * sizeof(float), stream);
  colsum_kernel<<<NNODES / 32, 128, 0, stream>>>(x, xsum);
  ground_kernel<<<1, 128, 0, stream>>>(x, xsum, Wglob, bglob, Wgr, bgr, G, dout);
  qblocks_kernel<<<64, 256, 0, stream>>>(x, G, Wd, bd, dout);
}